// Round 1
// baseline (981.766 us; speedup 1.0000x reference)
//
#include <hip/hip_runtime.h>
#include <math.h>

#define NN 2
#define DD 16
#define HH 32
#define WW 32
#define Cc 64
#define GGg 4
#define GCc 16
#define PPp 27
#define DIN 18
#define HIN 34
#define WIN 34
#define NVOX (NN*DD*HH*WW)      // 32768
#define ROWS 432                 // 324 offset rows + 108 mask rows
#define XP_FLOATS (NN*DIN*HIN*WIN*Cc)   // 2,663,424

// ---------------------------------------------------------------------------
// Transpose weight matrices so mat-vec weight reads are coalesced:
//   in_wT[c*64+j]  = in_w[j*64+c]
//   out_wT[c*64+j] = out_w[j*64+c]
//   cmbT[c*432+r]  = r<324 ? off_w[r*64+c] : mask_w[(r-324)*64+c]
// ---------------------------------------------------------------------------
__global__ void prep_weights(const float* __restrict__ in_w,
                             const float* __restrict__ out_w,
                             const float* __restrict__ off_w,
                             const float* __restrict__ mask_w,
                             float* __restrict__ in_wT,
                             float* __restrict__ out_wT,
                             float* __restrict__ cmbT) {
    int t = blockIdx.x * blockDim.x + threadIdx.x;
    int stride = gridDim.x * blockDim.x;
    for (int i = t; i < 64 * 64; i += stride) {
        int c = i >> 6, j = i & 63;
        in_wT[i]  = in_w[j * 64 + c];
        out_wT[i] = out_w[j * 64 + c];
    }
    for (int i = t; i < 64 * ROWS; i += stride) {
        int c = i / ROWS, r = i % ROWS;
        cmbT[i] = (r < 324) ? off_w[r * 64 + c] : mask_w[(r - 324) * 64 + c];
    }
}

// ---------------------------------------------------------------------------
// Zero the padded value buffer (ws is re-poisoned 0xAA before every launch).
// XP_FLOATS = 2,663,424 = 4 * 665,856 ; 665,856 = 256 * 2601
// ---------------------------------------------------------------------------
__global__ void zero_xp(float4* __restrict__ p) {
    int t = blockIdx.x * blockDim.x + threadIdx.x;
    p[t] = make_float4(0.f, 0.f, 0.f, 0.f);
}

// ---------------------------------------------------------------------------
// Value projection: xp[n, d+1, h+1, w+1, j] = sum_c input[...,c]*in_w[j,c] + in_b[j]
// One wave per voxel, 4 voxels per 256-thread block.
// ---------------------------------------------------------------------------
__global__ __launch_bounds__(256) void value_proj(
        const float* __restrict__ inp,
        const float* __restrict__ in_wT,
        const float* __restrict__ in_b,
        float* __restrict__ xp) {
    __shared__ float lx[4][64];
    int u = threadIdx.x >> 6;
    int j = threadIdx.x & 63;
    int vox = blockIdx.x * 4 + u;
    int w = vox & 31, h = (vox >> 5) & 31, d = (vox >> 10) & 15, n = vox >> 14;
    lx[u][j] = inp[(size_t)vox * 64 + j];
    __syncthreads();
    float acc = in_b[j];
    for (int c = 0; c < 64; ++c)
        acc = fmaf(lx[u][c], in_wT[c * 64 + j], acc);
    size_t o = ((((size_t)n * DIN + (d + 1)) * HIN + (h + 1)) * WIN + (w + 1)) * 64 + j;
    xp[o] = acc;
}

// ---------------------------------------------------------------------------
// Fused: depthwise conv + LN + GELU -> offset/mask matvec -> softmax ->
//        trilinear deformable sampling -> output projection.
// 256 threads = 4 waves; wave u owns voxel blockIdx.x*4+u.
// ---------------------------------------------------------------------------
__global__ __launch_bounds__(256) void dcn_main(
        const float* __restrict__ inp,     // (N,D,H,W,C)
        const float* __restrict__ dw_w,    // (C, 27)
        const float* __restrict__ dw_b,
        const float* __restrict__ ln_g,
        const float* __restrict__ ln_b,
        const float* __restrict__ off_b,   // (324,)
        const float* __restrict__ mask_b,  // (108,)
        const float* __restrict__ cmbT,    // (64, 432)
        const float* __restrict__ out_wT,  // (64, 64)
        const float* __restrict__ out_b,
        const float* __restrict__ xp,      // (N,18,34,34,64) padded values
        float* __restrict__ out) {
    __shared__ float s_dw[27 * 64];   // dw_w transposed: [k*64 + c]
    __shared__ float s_x1[4 * 64];
    __shared__ float s_om[4 * ROWS];  // per voxel: 324 offsets then 108 masks
    __shared__ float s_val[4 * 64];

    int t = threadIdx.x;
    int u = t >> 6, lane = t & 63;
    int vox = blockIdx.x * 4 + u;
    int w = vox & 31, h = (vox >> 5) & 31, d = (vox >> 10) & 15, n = vox >> 14;

    // stage depthwise weights transposed into LDS (coalesced global read)
    for (int i = t; i < 27 * 64; i += 256) {
        int c = i / 27, k = i % 27;
        s_dw[k * 64 + c] = dw_w[i];
    }
    __syncthreads();

    // ---- Phase 1: depthwise 3x3x3 conv + LayerNorm + exact GELU (lane = channel)
    {
        int c = lane;
        float acc = dw_b[c];
        for (int kd = 0; kd < 3; ++kd) {
            int dz = d + kd - 1;
            if (dz < 0 || dz >= DD) continue;
            for (int kh = 0; kh < 3; ++kh) {
                int hy = h + kh - 1;
                if (hy < 0 || hy >= HH) continue;
                for (int kw = 0; kw < 3; ++kw) {
                    int wx = w + kw - 1;
                    if (wx < 0 || wx >= WW) continue;
                    float v = inp[((((size_t)n * DD + dz) * HH + hy) * WW + wx) * 64 + c];
                    acc = fmaf(v, s_dw[(kd * 9 + kh * 3 + kw) * 64 + c], acc);
                }
            }
        }
        float s = acc, ss = acc * acc;
        for (int m = 1; m < 64; m <<= 1) {
            s  += __shfl_xor(s,  m, 64);
            ss += __shfl_xor(ss, m, 64);
        }
        float mu  = s * (1.f / 64.f);
        float var = ss * (1.f / 64.f) - mu * mu;
        float x1 = (acc - mu) * rsqrtf(var + 1e-6f) * ln_g[c] + ln_b[c];
        x1 = 0.5f * x1 * (1.f + erff(x1 * 0.70710678118654752f));   // exact GELU
        s_x1[u * 64 + c] = x1;
    }
    __syncthreads();

    // ---- Phase 2: offset + mask logits for all 4 voxels (432 rows)
    for (int r = t; r < ROWS; r += 256) {
        float a0 = 0.f, a1 = 0.f, a2 = 0.f, a3 = 0.f;
        for (int c = 0; c < 64; ++c) {
            float wv = cmbT[c * ROWS + r];
            a0 = fmaf(wv, s_x1[c],        a0);
            a1 = fmaf(wv, s_x1[64 + c],   a1);
            a2 = fmaf(wv, s_x1[128 + c],  a2);
            a3 = fmaf(wv, s_x1[192 + c],  a3);
        }
        float b = (r < 324) ? off_b[r] : mask_b[r - 324];
        s_om[0 * ROWS + r] = a0 + b;
        s_om[1 * ROWS + r] = a1 + b;
        s_om[2 * ROWS + r] = a2 + b;
        s_om[3 * ROWS + r] = a3 + b;
    }
    __syncthreads();

    // ---- Phase 3: softmax over the 27 points per (voxel, group)
    if (t < 16) {
        int v = t >> 2, g = t & 3;
        float* m = &s_om[v * ROWS + 324 + g * 27];
        float mx = m[0];
        for (int p = 1; p < 27; ++p) mx = fmaxf(mx, m[p]);
        float sum = 0.f;
        for (int p = 0; p < 27; ++p) { float e = expf(m[p] - mx); m[p] = e; sum += e; }
        float inv = 1.f / sum;
        for (int p = 0; p < 27; ++p) m[p] *= inv;
    }
    __syncthreads();

    // ---- Phase 4: deformable trilinear sampling (lane = channel = g*16+cc)
    {
        int g = lane >> 4;
        const float* om = &s_om[u * ROWS];
        float acc = 0.f;
        for (int p = 0; p < 27; ++p) {
            int ix = p / 9, iy = (p / 3) % 3, iz = p % 3;
            float ox = om[(g * 27 + p) * 3 + 0];
            float oy = om[(g * 27 + p) * 3 + 1];
            float oz = om[(g * 27 + p) * 3 + 2];
            // padded-space coords: w + 1 + (ix-1) + off
            float px = (float)(w + ix) + ox;
            float py = (float)(h + iy) + oy;
            float pz = (float)(d + iz) + oz;
            float msk = om[324 + g * 27 + p];
            float fx0 = floorf(px), fy0 = floorf(py), fz0 = floorf(pz);
            int x0 = (int)fx0, y0 = (int)fy0, z0 = (int)fz0;
            float fx = px - fx0, fy = py - fy0, fz = pz - fz0;
            for (int tz = 0; tz < 2; ++tz) {
                int zi = z0 + tz;
                if (zi < 0 || zi >= DIN) continue;
                float wz = tz ? fz : 1.f - fz;
                for (int ty = 0; ty < 2; ++ty) {
                    int yi = y0 + ty;
                    if (yi < 0 || yi >= HIN) continue;
                    float wy = ty ? fy : 1.f - fy;
                    for (int tx = 0; tx < 2; ++tx) {
                        int xi = x0 + tx;
                        if (xi < 0 || xi >= WIN) continue;
                        float wx2 = tx ? fx : 1.f - fx;
                        float v = xp[((((size_t)n * DIN + zi) * HIN + yi) * WIN + xi) * 64 + lane];
                        acc = fmaf(msk * wz * wy * wx2, v, acc);
                    }
                }
            }
        }
        s_val[u * 64 + lane] = acc;
    }
    __syncthreads();

    // ---- Phase 5: output projection
    {
        float acc = out_b[lane];
        for (int c = 0; c < 64; ++c)
            acc = fmaf(s_val[u * 64 + c], out_wT[c * 64 + lane], acc);
        out[(size_t)vox * 64 + lane] = acc;
    }
}

extern "C" void kernel_launch(void* const* d_in, const int* in_sizes, int n_in,
                              void* d_out, int out_size, void* d_ws, size_t ws_size,
                              hipStream_t stream) {
    const float* inp    = (const float*)d_in[0];
    const float* dw_w   = (const float*)d_in[1];
    const float* dw_b   = (const float*)d_in[2];
    const float* ln_g   = (const float*)d_in[3];
    const float* ln_b   = (const float*)d_in[4];
    const float* off_w  = (const float*)d_in[5];
    const float* off_b  = (const float*)d_in[6];
    const float* mask_w = (const float*)d_in[7];
    const float* mask_b = (const float*)d_in[8];
    const float* in_w   = (const float*)d_in[9];
    const float* in_b   = (const float*)d_in[10];
    const float* out_w  = (const float*)d_in[11];
    const float* out_b  = (const float*)d_in[12];

    float* ws     = (float*)d_ws;
    float* xp     = ws;                       // XP_FLOATS = 2,663,424
    float* in_wT  = xp + XP_FLOATS;           // 4096
    float* out_wT = in_wT + 4096;             // 4096
    float* cmbT   = out_wT + 4096;            // 27648
    float* outp   = (float*)d_out;

    prep_weights<<<32, 256, 0, stream>>>(in_w, out_w, off_w, mask_w, in_wT, out_wT, cmbT);
    zero_xp<<<2601, 256, 0, stream>>>((float4*)xp);
    value_proj<<<NVOX / 4, 256, 0, stream>>>(inp, in_wT, in_b, xp);
    dcn_main<<<NVOX / 4, 256, 0, stream>>>(inp, dw_w, dw_b, ln_g, ln_b,
                                           off_b, mask_b, cmbT, out_wT, out_b,
                                           xp, outp);
}

// Round 2
// 270.975 us; speedup vs baseline: 3.6231x; 3.6231x over previous
//
#include <hip/hip_runtime.h>
#include <math.h>

#define NN 2
#define DD 16
#define HH 32
#define WW 32
#define DIN 18
#define HIN 34
#define WIN 34
#define NVOX 32768
#define ROWS 432                 // 324 offset rows + 108 mask rows
#define XP_FLOATS (NN*DIN*HIN*WIN*64)   // 2,663,424

// ws layout (floats):
//   xp     [0, XP_FLOATS)
//   in_wT  +4096
//   out_wT +4096
//   cmbT   +27648
//   dwT    +1728
#define WS_IN_WT   XP_FLOATS
#define WS_OUT_WT  (WS_IN_WT + 4096)
#define WS_CMBT    (WS_OUT_WT + 4096)
#define WS_DWT     (WS_CMBT + 27648)

// ---------------------------------------------------------------------------
// Setup: zero the padded value buffer AND build transposed weight copies.
// grid = 2601 x 256 covers XP_FLOATS/4 = 665,856 float4 zeros; the low
// thread ids additionally do the (small) weight transposes.
// ---------------------------------------------------------------------------
__global__ __launch_bounds__(256) void setup(
        const float* __restrict__ in_w,  const float* __restrict__ out_w,
        const float* __restrict__ off_w, const float* __restrict__ mask_w,
        const float* __restrict__ dw_w,  float* __restrict__ ws) {
    int t = blockIdx.x * 256 + threadIdx.x;
    if (t < XP_FLOATS / 4)
        ((float4*)ws)[t] = make_float4(0.f, 0.f, 0.f, 0.f);
    if (t < 4096) {
        int c = t >> 6, j = t & 63;
        ws[WS_IN_WT  + t] = in_w [j * 64 + c];
        ws[WS_OUT_WT + t] = out_w[j * 64 + c];
    }
    if (t < 27648) {
        int c = t / ROWS, r = t % ROWS;
        ws[WS_CMBT + t] = (r < 324) ? off_w[r * 64 + c] : mask_w[(r - 324) * 64 + c];
    }
    if (t < 1728) {
        int k = t >> 6, c = t & 63;
        ws[WS_DWT + t] = dw_w[c * 27 + k];
    }
}

// ---------------------------------------------------------------------------
// Value projection: xp[n,d+1,h+1,w+1,j] = sum_c input[...,c]*in_w[j,c] + in_b[j]
// ---------------------------------------------------------------------------
__global__ __launch_bounds__(256) void value_proj(
        const float* __restrict__ inp,
        const float* __restrict__ ws_ro,
        const float* __restrict__ in_b,
        float* __restrict__ xp) {
    const float* in_wT = ws_ro + WS_IN_WT;
    __shared__ float lx[4][64];
    int u = threadIdx.x >> 6;
    int j = threadIdx.x & 63;
    int vox = blockIdx.x * 4 + u;
    int w = vox & 31, h = (vox >> 5) & 31, d = (vox >> 10) & 15, n = vox >> 14;
    lx[u][j] = inp[(size_t)vox * 64 + j];
    __syncthreads();
    float acc = in_b[j];
    #pragma unroll 8
    for (int c = 0; c < 64; ++c)
        acc = fmaf(lx[u][c], in_wT[c * 64 + j], acc);
    size_t o = ((((size_t)n * DIN + (d + 1)) * HIN + (h + 1)) * WIN + (w + 1)) * 64 + j;
    xp[o] = acc;
}

// ---------------------------------------------------------------------------
// Fused main: conv+LN+GELU -> heads matvec -> softmax -> sampling -> out proj
// 256 threads = 4 waves; wave u owns voxel blockIdx.x*4+u.
// ---------------------------------------------------------------------------
__global__ __launch_bounds__(256) void dcn_main(
        const float* __restrict__ inp,
        const float* __restrict__ dw_b,
        const float* __restrict__ ln_g,  const float* __restrict__ ln_b,
        const float* __restrict__ off_b, const float* __restrict__ mask_b,
        const float* __restrict__ ws_ro,
        const float* __restrict__ out_b,
        float* __restrict__ out) {
    const float* xp     = ws_ro;
    const float* out_wT = ws_ro + WS_OUT_WT;
    const float* cmbT   = ws_ro + WS_CMBT;
    const float* dwT    = ws_ro + WS_DWT;

    __shared__ float4 s_x1t4[64];          // x1 transposed: [c][vox 0..3]
    __shared__ float  s_om[4 * ROWS];      // per voxel: 324 offsets, 108 masks

    int t = threadIdx.x;
    int u = t >> 6, lane = t & 63;
    int vox = blockIdx.x * 4 + u;
    int w = vox & 31, h = (vox >> 5) & 31, d = (vox >> 10) & 15, n = vox >> 14;

    // ---- Stage 1: depthwise conv + LN + GELU (lane = channel, branches wave-uniform)
    {
        int c = lane;
        float acc = dw_b[c];
        #pragma unroll
        for (int kd = 0; kd < 3; ++kd) {
            int dz = d + kd - 1;
            if ((unsigned)dz >= DD) continue;
            #pragma unroll
            for (int kh = 0; kh < 3; ++kh) {
                int hy = h + kh - 1;
                if ((unsigned)hy >= HH) continue;
                #pragma unroll
                for (int kw = 0; kw < 3; ++kw) {
                    int wx = w + kw - 1;
                    if ((unsigned)wx >= WW) continue;
                    float v = inp[((((size_t)n * DD + dz) * HH + hy) * WW + wx) * 64 + c];
                    acc = fmaf(v, dwT[(kd * 9 + kh * 3 + kw) * 64 + c], acc);
                }
            }
        }
        float s = acc, ss = acc * acc;
        #pragma unroll
        for (int m = 1; m < 64; m <<= 1) {
            s  += __shfl_xor(s,  m, 64);
            ss += __shfl_xor(ss, m, 64);
        }
        float mu  = s * (1.f / 64.f);
        float var = ss * (1.f / 64.f) - mu * mu;
        float x1 = (acc - mu) * rsqrtf(var + 1e-6f) * ln_g[c] + ln_b[c];
        x1 = 0.5f * x1 * (1.f + erff(x1 * 0.70710678118654752f));
        ((float*)s_x1t4)[c * 4 + u] = x1;
    }
    __syncthreads();

    // ---- Stage 2: offset + mask logits, thread t handles rows t and t+256
    {
        int r0 = t;
        int r1c = (t + 256 < ROWS) ? t + 256 : ROWS - 1;   // clamped load row
        float a0 = 0.f, a1 = 0.f, a2 = 0.f, a3 = 0.f;
        float b0 = 0.f, b1 = 0.f, b2 = 0.f, b3 = 0.f;
        #pragma unroll 8
        for (int c = 0; c < 64; ++c) {
            float4 xv = s_x1t4[c];
            float wa = cmbT[c * ROWS + r0];
            float wb = cmbT[c * ROWS + r1c];
            a0 = fmaf(wa, xv.x, a0);
            a1 = fmaf(wa, xv.y, a1);
            a2 = fmaf(wa, xv.z, a2);
            a3 = fmaf(wa, xv.w, a3);
            b0 = fmaf(wb, xv.x, b0);
            b1 = fmaf(wb, xv.y, b1);
            b2 = fmaf(wb, xv.z, b2);
            b3 = fmaf(wb, xv.w, b3);
        }
        float bias0 = off_b[r0];                       // r0 < 256 < 324 always
        s_om[0 * ROWS + r0] = a0 + bias0;
        s_om[1 * ROWS + r0] = a1 + bias0;
        s_om[2 * ROWS + r0] = a2 + bias0;
        s_om[3 * ROWS + r0] = a3 + bias0;
        if (t + 256 < ROWS) {
            int r1 = t + 256;
            float bias1 = (r1 < 324) ? off_b[r1] : mask_b[r1 - 324];
            s_om[0 * ROWS + r1] = b0 + bias1;
            s_om[1 * ROWS + r1] = b1 + bias1;
            s_om[2 * ROWS + r1] = b2 + bias1;
            s_om[3 * ROWS + r1] = b3 + bias1;
        }
    }
    __syncthreads();

    // ---- Stage 3: softmax over 27 points per (voxel, group); 8 lanes each
    if (t < 128) {
        int v = t >> 5, g = (t >> 3) & 3, l = t & 7;
        float* m = &s_om[v * ROWS + 324 + g * 27];
        float mx = -1e30f;
        #pragma unroll
        for (int i = 0; i < 4; ++i) { int p = l + 8 * i; if (p < 27) mx = fmaxf(mx, m[p]); }
        mx = fmaxf(mx, __shfl_xor(mx, 1, 64));
        mx = fmaxf(mx, __shfl_xor(mx, 2, 64));
        mx = fmaxf(mx, __shfl_xor(mx, 4, 64));
        float e[4]; float sm = 0.f;
        #pragma unroll
        for (int i = 0; i < 4; ++i) {
            int p = l + 8 * i;
            e[i] = (p < 27) ? expf(m[p] - mx) : 0.f;
            sm += e[i];
        }
        sm += __shfl_xor(sm, 1, 64);
        sm += __shfl_xor(sm, 2, 64);
        sm += __shfl_xor(sm, 4, 64);
        float inv = 1.f / sm;
        #pragma unroll
        for (int i = 0; i < 4; ++i) { int p = l + 8 * i; if (p < 27) m[p] = e[i] * inv; }
    }
    __syncthreads();

    // ---- Stage 4: branchless trilinear sampling + shfl-based output projection
    {
        int g = lane >> 4;
        const float* omg = &s_om[u * ROWS] + g * 81;      // offsets for this group
        const float* mk  = &s_om[u * ROWS] + 324 + g * 27;
        size_t nbase = (size_t)n * (DIN * HIN * WIN * 64) + lane;
        float acc = 0.f;
        #pragma unroll 3
        for (int p = 0; p < 27; ++p) {
            int ix = p / 9, iy = (p / 3) % 3, iz = p % 3;
            float px = (float)(w + ix) + omg[3 * p + 0];
            float py = (float)(h + iy) + omg[3 * p + 1];
            float pz = (float)(d + iz) + omg[3 * p + 2];
            float msk = mk[p];
            float fx0 = floorf(px); int x0 = (int)fx0; float fx = px - fx0;
            float fy0 = floorf(py); int y0 = (int)fy0; float fy = py - fy0;
            float fz0 = floorf(pz); int z0 = (int)fz0; float fz = pz - fz0;
            float wx0 = ((unsigned)x0       < WIN) ? (1.f - fx) : 0.f;
            float wx1 = ((unsigned)(x0 + 1) < WIN) ? fx         : 0.f;
            float wy0 = ((unsigned)y0       < HIN) ? (1.f - fy) : 0.f;
            float wy1 = ((unsigned)(y0 + 1) < HIN) ? fy         : 0.f;
            float wz0 = ((unsigned)z0       < DIN) ? (1.f - fz) : 0.f;
            float wz1 = ((unsigned)(z0 + 1) < DIN) ? fz         : 0.f;
            int x0c = min(max(x0, 0), WIN - 1), x1c = min(max(x0 + 1, 0), WIN - 1);
            int y0c = min(max(y0, 0), HIN - 1), y1c = min(max(y0 + 1, 0), HIN - 1);
            int z0c = min(max(z0, 0), DIN - 1), z1c = min(max(z0 + 1, 0), DIN - 1);
            int r00 = (z0c * HIN + y0c) * WIN;
            int r01 = (z0c * HIN + y1c) * WIN;
            int r10 = (z1c * HIN + y0c) * WIN;
            int r11 = (z1c * HIN + y1c) * WIN;
            float t000 = xp[nbase + (size_t)(r00 + x0c) * 64];
            float t001 = xp[nbase + (size_t)(r00 + x1c) * 64];
            float t010 = xp[nbase + (size_t)(r01 + x0c) * 64];
            float t011 = xp[nbase + (size_t)(r01 + x1c) * 64];
            float t100 = xp[nbase + (size_t)(r10 + x0c) * 64];
            float t101 = xp[nbase + (size_t)(r10 + x1c) * 64];
            float t110 = xp[nbase + (size_t)(r11 + x0c) * 64];
            float t111 = xp[nbase + (size_t)(r11 + x1c) * 64];
            float s00 = wx0 * t000 + wx1 * t001;
            float s01 = wx0 * t010 + wx1 * t011;
            float s10 = wx0 * t100 + wx1 * t101;
            float s11 = wx0 * t110 + wx1 * t111;
            float sy0 = wy0 * s00 + wy1 * s01;
            float sy1 = wy0 * s10 + wy1 * s11;
            acc = fmaf(msk, wz0 * sy0 + wz1 * sy1, acc);
        }
        // output projection: o[lane] = out_b[lane] + sum_c val[c] * out_w[lane, c]
        float o = out_b[lane];
        #pragma unroll 8
        for (int c = 0; c < 64; ++c) {
            float vc = __shfl(acc, c, 64);
            o = fmaf(vc, out_wT[c * 64 + lane], o);
        }
        out[(size_t)vox * 64 + lane] = o;
    }
}

extern "C" void kernel_launch(void* const* d_in, const int* in_sizes, int n_in,
                              void* d_out, int out_size, void* d_ws, size_t ws_size,
                              hipStream_t stream) {
    const float* inp    = (const float*)d_in[0];
    const float* dw_w   = (const float*)d_in[1];
    const float* dw_b   = (const float*)d_in[2];
    const float* ln_g   = (const float*)d_in[3];
    const float* ln_b   = (const float*)d_in[4];
    const float* off_w  = (const float*)d_in[5];
    const float* off_b  = (const float*)d_in[6];
    const float* mask_w = (const float*)d_in[7];
    const float* mask_b = (const float*)d_in[8];
    const float* in_b   = (const float*)d_in[10];
    const float* in_w   = (const float*)d_in[9];
    const float* out_w  = (const float*)d_in[11];
    const float* out_b  = (const float*)d_in[12];

    float* ws = (float*)d_ws;

    setup<<<2601, 256, 0, stream>>>(in_w, out_w, off_w, mask_w, dw_w, ws);
    value_proj<<<NVOX / 4, 256, 0, stream>>>(inp, ws, in_b, ws);
    dcn_main<<<NVOX / 4, 256, 0, stream>>>(inp, dw_b, ln_g, ln_b,
                                           off_b, mask_b, ws, out_b,
                                           (float*)d_out);
}